// Round 6
// baseline (488.248 us; speedup 1.0000x reference)
//
#include <hip/hip_runtime.h>
#include <hip/hip_bf16.h>
#include <cstdint>

#define DEV static __device__ __forceinline__

typedef __attribute__((ext_vector_type(8))) short short8;
typedef __attribute__((ext_vector_type(4))) float f32x4;
typedef __attribute__((ext_vector_type(2))) float f32x2;

DEV uint32_t bf16rne(float f) {
    uint32_t u = __float_as_uint(f);
    uint32_t r = u + 0x7FFFu + ((u >> 16) & 1u);
    return r >> 16;
}
DEV float bf16tof(uint32_t h) { return __uint_as_float((h & 0xFFFFu) << 16); }
DEV float hsig(float z) { return fminf(fmaxf(0.2f * z + 0.5f, 0.f), 1.f); }
DEV float lrelu(float x) { return x >= 0.f ? x : 0.3f * x; }
DEV float ftanh(float x) {
    float e = __expf(2.0f * x);
    return 1.0f - 2.0f * __builtin_amdgcn_rcpf(e + 1.0f);
}

DEV void gload16(const void* g, void* l) {
    __builtin_amdgcn_global_load_lds(
        reinterpret_cast<const __attribute__((address_space(1))) uint32_t*>(
            reinterpret_cast<uintptr_t>(g)),
        reinterpret_cast<__attribute__((address_space(3))) uint32_t*>(
            reinterpret_cast<uintptr_t>(l)),
        16, 0, 0);
}

#define HH 82
#define WW 67
#define PIX (HH * WW)   // 5494
#define BB 64
#define TT 24

// slot j (0..68) -> swizzled byte offset within a 1104-B LDS row
#define SWZ(j) (((j) * 16) ^ ((((j) >> 3) & 7) << 4))

// ---------------- Kernel 1: xz = conv(x_t, wx) + b_lstm, LDS v3 ----------------
// block = 15-row strip; LDS bf16 [17 rows][69 slots][8 ch-slots], XOR-swizzled.
// compute thread = 4-px run: 18 ds_read_b128, weights amortized over 4 px.
__global__ __launch_bounds__(256) void k_xz(
    const float* __restrict__ inp, const float* __restrict__ wx,
    const float* __restrict__ bl, uint2* __restrict__ xz)
{
    __shared__ uint4 s4[17 * 69 + 1];
    char* s = (char*)s4;
    const int bt = blockIdx.x / 6, strip = blockIdx.x % 6;
    const int r0 = strip * 15;
    const int tid = threadIdx.x;
    const float* img = inp + (size_t)bt * (PIX * 6);

    // zero halo slots j=0 and j=68 of each of the 17 rows
    if (tid < 34) {
        int lr = tid >> 1, side = tid & 1;
        *(uint4*)(s + lr * 1104 + (side ? SWZ(68) : SWZ(0))) = make_uint4(0, 0, 0, 0);
    }
    // stage 17 rows x 201 float2 (coalesced) -> packed bf16 pairs
    for (int i = tid; i < 17 * 201; i += 256) {
        int lr = i / 201, i2 = i % 201;
        int gr = r0 - 1 + lr;
        float2 v = make_float2(0.f, 0.f);
        if (gr >= 0 && gr < HH)
            v = *(const float2*)(img + (size_t)gr * 402 + i2 * 2);
        int p = i2 / 3, c2 = i2 % 3;
        uint32_t pk = bf16rne(v.x) | (bf16rne(v.y) << 16);
        *(uint32_t*)(s + lr * 1104 + SWZ(p + 1) + c2 * 4) = pk;
    }
    __syncthreads();

    if (tid >= 255) return;
    const int ry = tid / 17, rx = tid % 17;
    const int y = r0 + ry;
    if (y >= HH) return;
    const int ox0 = rx * 4;

    // window: 3 rows x 6 slots of packed bf16 (slot = img px ox0-1+q)
    uint4 w[3][6];
    #pragma unroll
    for (int dy = 0; dy < 3; ++dy)
        #pragma unroll
        for (int q = 0; q < 6; ++q)
            w[dy][q] = *(const uint4*)(s + (ry + dy) * 1104 + SWZ(ox0 + q));

    f32x2 a01[4], a23[4];
    const f32x2 bias01 = {bl[0], bl[1]};
    const f32x2 bias23 = {bl[2], bl[3]};
    #pragma unroll
    for (int xo = 0; xo < 4; ++xo) { a01[xo] = bias01; a23[xo] = bias23; }

    #pragma unroll
    for (int dy = 0; dy < 3; ++dy) {
        #pragma unroll
        for (int t = 0; t < 3; ++t) {
            const float* w6 = wx + (dy * 3 + t) * 24;
            #pragma unroll
            for (int ci = 0; ci < 6; ++ci) {
                const f32x2 w01 = *(const f32x2*)(w6 + ci * 4);
                const f32x2 w23 = *(const f32x2*)(w6 + ci * 4 + 2);
                #pragma unroll
                for (int xo = 0; xo < 4; ++xo) {
                    const uint32_t word = ((const uint32_t*)&w[dy][xo + t])[ci >> 1];
                    const float sv = __uint_as_float(
                        (ci & 1) ? (word & 0xFFFF0000u) : (word << 16));
                    a01[xo] += sv * w01;
                    a23[xo] += sv * w23;
                }
            }
        }
    }

    uint2* orow = xz + ((size_t)bt * HH + y) * WW;
    const int npx = (ox0 + 4 <= WW) ? 4 : (WW - ox0);
    #pragma unroll
    for (int xo = 0; xo < 4; ++xo) {
        if (xo < npx) {
            uint32_t lo = bf16rne(a01[xo][0]) | (bf16rne(a01[xo][1]) << 16);
            uint32_t hi = bf16rne(a23[xo][0]) | (bf16rne(a23[xo][1]) << 16);
            orow[ox0 + xo] = make_uint2(lo, hi);
        }
    }
}

// ---------------- Kernel 2: sequential LSTM, one block per batch image ----------------
__global__ __launch_bounds__(1024) void k_lstm(
    const uint2* __restrict__ xz, const float* __restrict__ wh,
    float* __restrict__ hout)
{
    __shared__ float hb[2][PIX];
    const int b = blockIdx.x;
    const int tid = threadIdx.x;
    float whr[9][4];
    #pragma unroll
    for (int k = 0; k < 9; ++k)
        #pragma unroll
        for (int g = 0; g < 4; ++g) whr[k][g] = wh[k * 4 + g];

    for (int i = tid; i < PIX; i += 1024) hb[0][i] = 0.f;

    const bool active = tid < 984;
    const int ry = tid / 12;
    const int x0 = (tid % 12) * 6;
    const int len = active ? ((x0 + 6 <= WW) ? 6 : (WW - x0)) : 0;
    float c[6];
    #pragma unroll
    for (int j = 0; j < 6; ++j) c[j] = 0.f;
    __syncthreads();

    #pragma unroll 1
    for (int t = 0; t < TT; ++t) {
        const int cur = t & 1;
        if (active) {
            float z[6][4];
            const uint2* zb = xz + ((size_t)b * TT + t) * PIX + ry * WW;
            #pragma unroll
            for (int j = 0; j < 6; ++j) {
                uint2 zp = zb[(x0 + j < WW) ? (x0 + j) : (WW - 1)];
                z[j][0] = bf16tof(zp.x); z[j][1] = bf16tof(zp.x >> 16);
                z[j][2] = bf16tof(zp.y); z[j][3] = bf16tof(zp.y >> 16);
            }
            #pragma unroll
            for (int ky = 0; ky < 3; ++ky) {
                int iy = ry + ky - 1;
                if (iy < 0 || iy >= HH) continue;
                const float* hr = &hb[cur][iy * WW];
                #pragma unroll
                for (int dx = -1; dx < 7; ++dx) {
                    int xi = x0 + dx;
                    if (xi < 0 || xi >= WW) continue;
                    float hv = hr[xi];
                    #pragma unroll
                    for (int kx = 0; kx < 3; ++kx) {
                        int xo = dx - kx + 1;
                        if (xo < 0 || xo > 5) continue;
                        #pragma unroll
                        for (int g = 0; g < 4; ++g)
                            z[xo][g] = fmaf(hv, whr[ky * 3 + kx][g], z[xo][g]);
                    }
                }
            }
            float* hw = &hb[cur ^ 1][ry * WW];
            #pragma unroll
            for (int j = 0; j < 6; ++j) {
                float fi = hsig(z[j][0]), ff = hsig(z[j][1]), fo = hsig(z[j][3]);
                float cn = ff * c[j] + fi * ftanh(z[j][2]);
                c[j] = cn;
                if (j < len) hw[x0 + j] = fo * ftanh(cn);
            }
        }
        __syncthreads();
    }
    for (int i = tid; i < PIX; i += 1024)
        hout[(size_t)b * PIX + i] = hb[0][i];
}

// ---------------- Kernel 3: conv1 5x5 s2 SAME, 6->64, +bias, LeakyReLU ----------------
// writes bf16 into padded x1p[64][45][37][64] at (y+2, x+1)
__global__ __launch_bounds__(256) void k_conv1(
    const float* __restrict__ hin, const float* __restrict__ tar,
    const float* __restrict__ w1, const float* __restrict__ b1,
    ushort* __restrict__ x1p)
{
    int wid = (blockIdx.x * 256 + threadIdx.x) >> 6;
    int lane = threadIdx.x & 63;
    int b = wid / 41, y = wid % 41;
    float acc[34];
    float bias = b1[lane];
    #pragma unroll
    for (int x = 0; x < 34; ++x) acc[x] = bias;
    #pragma unroll 1
    for (int ky = 0; ky < 5; ++ky) {
        int iy = 2 * y + ky - 1;
        if (iy < 0 || iy >= HH) continue;
        const float* hrow = hin + (size_t)b * PIX + iy * WW;
        const float* trow = tar + ((size_t)b * PIX + iy * WW) * 5;
        #pragma unroll 1
        for (int kx = 0; kx < 5; ++kx) {
            float w[6];
            #pragma unroll
            for (int ci = 0; ci < 6; ++ci)
                w[ci] = w1[((ky * 5 + kx) * 6 + ci) * 64 + lane];
            #pragma unroll
            for (int x = 0; x < 34; ++x) {
                int ix = 2 * x + kx - 2;
                if (ix < 0 || ix >= WW) continue;
                float v0 = hrow[ix];
                acc[x] += v0 * w[0];
                #pragma unroll
                for (int c = 0; c < 5; ++c)
                    acc[x] += trow[ix * 5 + c] * w[c + 1];
            }
        }
    }
    ushort* obase = x1p + ((size_t)(b * 45 + y + 2) * 37) * 64;
    #pragma unroll
    for (int x = 0; x < 34; ++x)
        obase[(x + 1) * 64 + lane] = (ushort)bf16rne(lrelu(acc[x]));
}

// ---------------- Weight transpose+cvt: wt[n][k] = bf16(w[k][n]) ----------------
__global__ __launch_bounds__(256) void k_wt(
    const float* __restrict__ w, ushort* __restrict__ wt, int K, int N)
{
    int idx = blockIdx.x * 256 + threadIdx.x;
    if (idx >= K * N) return;
    int n = idx / K, k = idx % K;
    wt[idx] = (ushort)bf16rne(w[(size_t)k * N + n]);
}

// ---------------- MFMA implicit-GEMM conv (conv2 / conv3) ----------------
template<bool IS3>
__global__ __launch_bounds__(256) void k_convm(
    const ushort* __restrict__ Ain, const ushort* __restrict__ Bt,
    const float* __restrict__ p0, const float* __restrict__ p1,
    const float* __restrict__ p2, const float* __restrict__ p3,
    ushort* __restrict__ outp)
{
    constexpr int OH = IS3 ? 20 : 21, OW = IS3 ? 16 : 17;
    constexpr int PH = IS3 ? 23 : 45, PW = IS3 ? 19 : 37;
    constexpr int CIN = IS3 ? 128 : 64;
    constexpr int KW_ = IS3 ? 4 : 5;
    constexpr int KK  = IS3 ? 16 : 25;
    constexpr int STR = IS3 ? 1 : 2;
    constexpr int HALVES = CIN / 64;
    constexpr int MPB = OH * OW;
    constexpr int M = 64 * MPB;
    constexpr int KTOT = KK * CIN;

    __shared__ ushort At[128 * 64];
    __shared__ ushort Bl[128 * 64];

    const int tid = threadIdx.x;
    const int wid = tid >> 6, lane = tid & 63;
    const int m0 = blockIdx.x * 128;
    const int n0 = blockIdx.y * 128;
    const int wr = wid >> 1, wc = wid & 1;

    const int swz = (((lane & 7) ^ ((lane >> 3) & 7)) << 3);

    int arow_base[4], brow_base[4];
    #pragma unroll
    for (int i = 0; i < 4; ++i) {
        int row = wid * 32 + i * 8 + (lane >> 3);
        int m = m0 + row; if (m > M - 1) m = M - 1;
        int b = m / MPB, r = m % MPB;
        int y = r / OW, x = r % OW;
        arow_base[i] = ((b * PH + y * STR) * PW + x * STR) * CIN;
        brow_base[i] = (n0 + row) * KTOT;
    }

    f32x4 acc[4][4];
    #pragma unroll
    for (int i = 0; i < 4; ++i)
        #pragma unroll
        for (int j = 0; j < 4; ++j) acc[i][j] = (f32x4){0.f, 0.f, 0.f, 0.f};

    #pragma unroll 1
    for (int kp = 0; kp < KK; ++kp) {
        const int ky = kp / KW_, kx = kp % KW_;
        const int aoff = (ky * PW + kx) * CIN;
        #pragma unroll
        for (int h = 0; h < HALVES; ++h) {
            const int koff = h * 64;
            #pragma unroll
            for (int i = 0; i < 4; ++i) {
                gload16(Ain + arow_base[i] + aoff + koff + swz,
                        (void*)(At + (wid * 32 + i * 8) * 64));
                gload16(Bt + brow_base[i] + kp * CIN + koff + swz,
                        (void*)(Bl + (wid * 32 + i * 8) * 64));
            }
            __syncthreads();
            #pragma unroll
            for (int ks = 0; ks < 2; ++ks) {
                short8 af[4], bf[4];
                const int lc = ks * 64 + ((lane >> 4) << 4);
                #pragma unroll
                for (int mf = 0; mf < 4; ++mf) {
                    int row = wr * 64 + mf * 16 + (lane & 15);
                    af[mf] = *(const short8*)((const char*)At + row * 128 + (lc ^ ((row & 7) << 4)));
                }
                #pragma unroll
                for (int nf = 0; nf < 4; ++nf) {
                    int row = wc * 64 + nf * 16 + (lane & 15);
                    bf[nf] = *(const short8*)((const char*)Bl + row * 128 + (lc ^ ((row & 7) << 4)));
                }
                #pragma unroll
                for (int mf = 0; mf < 4; ++mf)
                    #pragma unroll
                    for (int nf = 0; nf < 4; ++nf)
                        acc[mf][nf] = __builtin_amdgcn_mfma_f32_16x16x32_bf16(
                            af[mf], bf[nf], acc[mf][nf], 0, 0, 0);
            }
            __syncthreads();
        }
    }

    if (IS3) {
        #pragma unroll
        for (int nf = 0; nf < 4; ++nf) {
            int n = n0 + wc * 64 + nf * 16 + (lane & 15);
            float sc = p0[n] * rsqrtf(p3[n] + 1e-3f);
            float sh = p1[n] - p2[n] * sc;
            #pragma unroll
            for (int mf = 0; mf < 4; ++mf) {
                int mbase = m0 + wr * 64 + mf * 16 + ((lane >> 4) << 2);
                #pragma unroll
                for (int r = 0; r < 4; ++r) {
                    float v = lrelu(acc[mf][nf][r] * sc + sh);
                    outp[(size_t)(mbase + r) * 512 + n] = (ushort)bf16rne(v);
                }
            }
        }
    } else {
        #pragma unroll
        for (int nf = 0; nf < 4; ++nf) {
            int n = wc * 64 + nf * 16 + (lane & 15);
            float bias = p0[n];
            #pragma unroll
            for (int mf = 0; mf < 4; ++mf) {
                int mbase = m0 + wr * 64 + mf * 16 + ((lane >> 4) << 2);
                #pragma unroll
                for (int r = 0; r < 4; ++r) {
                    int m = mbase + r;
                    if (m < M) {
                        int b = m / MPB, rr = m % MPB;
                        int y = rr / OW, x = rr % OW;
                        float v = lrelu(acc[mf][nf][r] + bias);
                        outp[((size_t)((b * 23) + (y + 1)) * 19 + (x + 1)) * 128 + n] =
                            (ushort)bf16rne(v);
                    }
                }
            }
        }
    }
}

// ---------------- Kernel 6: pad1 + conv4 4x4 VALID, 512->1, +bias (bf16 in) ----------------
__global__ __launch_bounds__(64) void k_conv4(
    const ushort* __restrict__ x3, const float* __restrict__ w4,
    const float* __restrict__ b4, float* __restrict__ out)
{
    int b = blockIdx.x / 19, y = blockIdx.x % 19;
    int lane = threadIdx.x;
    int c0 = lane * 8;
    float acc[15];
    #pragma unroll
    for (int x = 0; x < 15; ++x) acc[x] = 0.f;
    #pragma unroll 1
    for (int ky = 0; ky < 4; ++ky) {
        int iy = y + ky - 1;
        if (iy < 0 || iy >= 20) continue;
        float w[4][8];
        #pragma unroll
        for (int kx = 0; kx < 4; ++kx) {
            const float4 wa = *(const float4*)(w4 + (ky * 4 + kx) * 512 + c0);
            const float4 wb = *(const float4*)(w4 + (ky * 4 + kx) * 512 + c0 + 4);
            w[kx][0] = wa.x; w[kx][1] = wa.y; w[kx][2] = wa.z; w[kx][3] = wa.w;
            w[kx][4] = wb.x; w[kx][5] = wb.y; w[kx][6] = wb.z; w[kx][7] = wb.w;
        }
        #pragma unroll 1
        for (int ix = 0; ix < 16; ++ix) {
            uint4 u = *(const uint4*)(x3 + ((size_t)(b * 20 + iy) * 16 + ix) * 512 + c0);
            float v[8];
            v[0] = bf16tof(u.x); v[1] = bf16tof(u.x >> 16);
            v[2] = bf16tof(u.y); v[3] = bf16tof(u.y >> 16);
            v[4] = bf16tof(u.z); v[5] = bf16tof(u.z >> 16);
            v[6] = bf16tof(u.w); v[7] = bf16tof(u.w >> 16);
            #pragma unroll
            for (int kx = 0; kx < 4; ++kx) {
                int x = ix - kx + 1;
                if (x < 0 || x > 14) continue;
                float s = 0.f;
                #pragma unroll
                for (int c = 0; c < 8; ++c) s = fmaf(v[c], w[kx][c], s);
                acc[x] += s;
            }
        }
    }
    float bias = b4[0];
    #pragma unroll
    for (int x = 0; x < 15; ++x) {
        float s = acc[x];
        #pragma unroll
        for (int off = 32; off > 0; off >>= 1)
            s += __shfl_down(s, off);
        if (lane == 0) out[(size_t)blockIdx.x * 15 + x] = s + bias;
    }
}

extern "C" void kernel_launch(void* const* d_in, const int* in_sizes, int n_in,
                              void* d_out, int out_size, void* d_ws, size_t ws_size,
                              hipStream_t stream)
{
    const float* inp  = (const float*)d_in[0];
    const float* tar  = (const float*)d_in[1];
    const float* wx   = (const float*)d_in[2];
    const float* wh   = (const float*)d_in[3];
    const float* bl   = (const float*)d_in[4];
    const float* w1   = (const float*)d_in[5];
    const float* b1   = (const float*)d_in[6];
    const float* w2   = (const float*)d_in[7];
    const float* b2   = (const float*)d_in[8];
    const float* w3   = (const float*)d_in[9];
    const float* gam  = (const float*)d_in[10];
    const float* bet  = (const float*)d_in[11];
    const float* mean = (const float*)d_in[12];
    const float* var  = (const float*)d_in[13];
    const float* w4   = (const float*)d_in[14];
    const float* b4   = (const float*)d_in[15];
    float* out = (float*)d_out;

    char* ws = (char*)d_ws;
    uint2*  xz   = (uint2*)(ws);
    ushort* x3b  = (ushort*)(ws);
    float*  hfin = (float*)(ws + 67510272);
    ushort* x1p  = (ushort*)(ws + 68916736);
    ushort* x2p  = (ushort*)(ws + 82556416);
    ushort* w2t  = (ushort*)(ws + 89716224);
    ushort* w3t  = (ushort*)(ws + 90125824);

    hipMemsetAsync(x1p, 0, 13639680, stream);
    hipMemsetAsync(x2p, 0, 7159808, stream);

    k_wt<<<(128 * 1600 + 255) / 256, 256, 0, stream>>>(w2, w2t, 1600, 128);
    k_wt<<<(512 * 2048 + 255) / 256, 256, 0, stream>>>(w3, w3t, 2048, 512);

    k_xz<<<1536 * 6, 256, 0, stream>>>(inp, wx, bl, xz);
    k_lstm<<<BB, 1024, 0, stream>>>(xz, wh, hfin);
    k_conv1<<<656, 256, 0, stream>>>(hfin, tar, w1, b1, x1p);

    dim3 g2(179, 1);
    k_convm<false><<<g2, 256, 0, stream>>>(x1p, w2t, b2, nullptr, nullptr, nullptr, x2p);
    dim3 g3(160, 4);
    k_convm<true><<<g3, 256, 0, stream>>>(x2p, w3t, gam, bet, mean, var, x3b);

    k_conv4<<<BB * 19, 64, 0, stream>>>(x3b, w4, b4, out);
}

// Round 7
// 455.893 us; speedup vs baseline: 1.0710x; 1.0710x over previous
//
#include <hip/hip_runtime.h>
#include <hip/hip_bf16.h>
#include <cstdint>

#define DEV static __device__ __forceinline__

typedef __attribute__((ext_vector_type(8))) short short8;
typedef __attribute__((ext_vector_type(4))) float f32x4;
typedef __attribute__((ext_vector_type(2))) float f32x2;

DEV uint32_t bf16rne(float f) {
    uint32_t u = __float_as_uint(f);
    uint32_t r = u + 0x7FFFu + ((u >> 16) & 1u);
    return r >> 16;
}
DEV float bf16tof(uint32_t h) { return __uint_as_float((h & 0xFFFFu) << 16); }
DEV float hsig(float z) { return fminf(fmaxf(0.2f * z + 0.5f, 0.f), 1.f); }
DEV float lrelu(float x) { return x >= 0.f ? x : 0.3f * x; }
DEV float ftanh(float x) {
    float e = __expf(2.0f * x);
    return 1.0f - 2.0f * __builtin_amdgcn_rcpf(e + 1.0f);
}

DEV void gload16(const void* g, void* l) {
    __builtin_amdgcn_global_load_lds(
        reinterpret_cast<const __attribute__((address_space(1))) uint32_t*>(
            reinterpret_cast<uintptr_t>(g)),
        reinterpret_cast<__attribute__((address_space(3))) uint32_t*>(
            reinterpret_cast<uintptr_t>(l)),
        16, 0, 0);
}

#define HH 82
#define WW 67
#define PIX (HH * WW)   // 5494
#define BB 64
#define TT 24

// ---------------- Kernel 1: xz = conv(x_t, wx) + b_lstm, LDS v4 ----------------
// fp32 LDS [17 rows][70 px-slots][6ch] (slot p = img px p-1, slots 0/68/69 zero).
// Staging: coalesced float2. Compute: thread = 4-px run, round-4 inner loop,
// 54 ds_read_b64 (4-way conflicts, benign), weights wave-uniform.
#define XSTRIDE 420   // floats per LDS row (70 slots * 6)
__global__ __launch_bounds__(256) void k_xz(
    const float* __restrict__ inp, const float* __restrict__ wx,
    const float* __restrict__ bl, uint2* __restrict__ xz)
{
    __shared__ float s[17 * XSTRIDE];   // 28,560 B
    const int bt = blockIdx.x / 6, strip = blockIdx.x % 6;
    const int r0 = strip * 15;
    const int tid = threadIdx.x;
    const float* img = inp + (size_t)bt * (PIX * 6);

    // zero halo slots 0, 68, 69 of each of the 17 rows (51 slot-clears)
    if (tid < 51) {
        int lr = tid / 3, which = tid % 3;
        int slot = (which == 0) ? 0 : (67 + which);   // 0, 68, 69
        float* q = s + lr * XSTRIDE + slot * 6;
        #pragma unroll
        for (int c = 0; c < 6; ++c) q[c] = 0.f;
    }
    // stage 17 rows x 201 float2 (coalesced); row lr = img row r0-1+lr
    for (int i = tid; i < 17 * 201; i += 256) {
        int lr = i / 201, j = i % 201;
        int gr = r0 - 1 + lr;
        float2 v = make_float2(0.f, 0.f);
        if (gr >= 0 && gr < HH)
            v = *(const float2*)(img + (size_t)gr * 402 + j * 2);
        *(float2*)(s + lr * XSTRIDE + 6 + j * 2) = v;
    }
    __syncthreads();

    if (tid >= 255) return;
    const int ry = tid / 17, rx = tid % 17;
    const int y = r0 + ry;
    if (y >= HH) return;
    const int ox0 = rx * 4;

    f32x2 a01[4], a23[4];
    const f32x2 bias01 = {bl[0], bl[1]};
    const f32x2 bias23 = {bl[2], bl[3]};
    #pragma unroll
    for (int xo = 0; xo < 4; ++xo) { a01[xo] = bias01; a23[xo] = bias23; }

    #pragma unroll
    for (int dy = 0; dy < 3; ++dy) {
        // window: slots ox0 .. ox0+5 of LDS row ry+dy (= img px ox0-1 .. ox0+4)
        const float* row = s + (ry + dy) * XSTRIDE + ox0 * 6;
        f32x2 v[6][3];
        #pragma unroll
        for (int p = 0; p < 6; ++p) {
            v[p][0] = *(const f32x2*)(row + p * 6);
            v[p][1] = *(const f32x2*)(row + p * 6 + 2);
            v[p][2] = *(const f32x2*)(row + p * 6 + 4);
        }
        #pragma unroll
        for (int kx = 0; kx < 3; ++kx) {
            const float* w6 = wx + (dy * 3 + kx) * 24;
            #pragma unroll
            for (int ci = 0; ci < 6; ++ci) {
                const f32x2 w01 = *(const f32x2*)(w6 + ci * 4);
                const f32x2 w23 = *(const f32x2*)(w6 + ci * 4 + 2);
                #pragma unroll
                for (int xo = 0; xo < 4; ++xo) {
                    const float sv = v[xo + kx][ci >> 1][ci & 1];
                    a01[xo] += sv * w01;
                    a23[xo] += sv * w23;
                }
            }
        }
    }

    uint2* orow = xz + ((size_t)bt * HH + y) * WW;
    const int npx = (ox0 + 4 <= WW) ? 4 : (WW - ox0);
    uint32_t lo[4], hi[4];
    #pragma unroll
    for (int xo = 0; xo < 4; ++xo) {
        lo[xo] = bf16rne(a01[xo][0]) | (bf16rne(a01[xo][1]) << 16);
        hi[xo] = bf16rne(a23[xo][0]) | (bf16rne(a23[xo][1]) << 16);
    }
    if (npx == 4) {
        *(uint4*)(orow + ox0)     = make_uint4(lo[0], hi[0], lo[1], hi[1]);
        *(uint4*)(orow + ox0 + 2) = make_uint4(lo[2], hi[2], lo[3], hi[3]);
    } else {
        #pragma unroll
        for (int xo = 0; xo < 4; ++xo)
            if (xo < npx) orow[ox0 + xo] = make_uint2(lo[xo], hi[xo]);
    }
}

// ---------------- Kernel 2: sequential LSTM, one block per batch image ----------------
__global__ __launch_bounds__(1024) void k_lstm(
    const uint2* __restrict__ xz, const float* __restrict__ wh,
    float* __restrict__ hout)
{
    __shared__ float hb[2][PIX];
    const int b = blockIdx.x;
    const int tid = threadIdx.x;
    float whr[9][4];
    #pragma unroll
    for (int k = 0; k < 9; ++k)
        #pragma unroll
        for (int g = 0; g < 4; ++g) whr[k][g] = wh[k * 4 + g];

    for (int i = tid; i < PIX; i += 1024) hb[0][i] = 0.f;

    const bool active = tid < 984;
    const int ry = tid / 12;
    const int x0 = (tid % 12) * 6;
    const int len = active ? ((x0 + 6 <= WW) ? 6 : (WW - x0)) : 0;
    float c[6];
    #pragma unroll
    for (int j = 0; j < 6; ++j) c[j] = 0.f;
    __syncthreads();

    #pragma unroll 1
    for (int t = 0; t < TT; ++t) {
        const int cur = t & 1;
        if (active) {
            float z[6][4];
            const uint2* zb = xz + ((size_t)b * TT + t) * PIX + ry * WW;
            // unconditional loads; OOB-for-tail-run stays inside workspace and
            // feeds only len-masked lanes
            #pragma unroll
            for (int j = 0; j < 6; ++j) {
                uint2 zp = zb[x0 + j];
                z[j][0] = bf16tof(zp.x); z[j][1] = bf16tof(zp.x >> 16);
                z[j][2] = bf16tof(zp.y); z[j][3] = bf16tof(zp.y >> 16);
            }
            #pragma unroll
            for (int ky = 0; ky < 3; ++ky) {
                int iy = ry + ky - 1;
                if (iy < 0 || iy >= HH) continue;
                const float* hr = &hb[cur][iy * WW];
                #pragma unroll
                for (int dx = -1; dx < 7; ++dx) {
                    int xi = x0 + dx;
                    if (xi < 0 || xi >= WW) continue;
                    float hv = hr[xi];
                    #pragma unroll
                    for (int kx = 0; kx < 3; ++kx) {
                        int xo = dx - kx + 1;
                        if (xo < 0 || xo > 5) continue;
                        #pragma unroll
                        for (int g = 0; g < 4; ++g)
                            z[xo][g] = fmaf(hv, whr[ky * 3 + kx][g], z[xo][g]);
                    }
                }
            }
            float* hw = &hb[cur ^ 1][ry * WW];
            #pragma unroll
            for (int j = 0; j < 6; ++j) {
                float fi = hsig(z[j][0]), ff = hsig(z[j][1]), fo = hsig(z[j][3]);
                float cn = ff * c[j] + fi * ftanh(z[j][2]);
                c[j] = cn;
                if (j < len) hw[x0 + j] = fo * ftanh(cn);
            }
        }
        __syncthreads();
    }
    for (int i = tid; i < PIX; i += 1024)
        hout[(size_t)b * PIX + i] = hb[0][i];
}

// ---------------- Kernel 3: conv1 5x5 s2 SAME, 6->64, +bias, LeakyReLU ----------------
// writes bf16 into padded x1p[64][45][37][64] at (y+2, x+1)
__global__ __launch_bounds__(256) void k_conv1(
    const float* __restrict__ hin, const float* __restrict__ tar,
    const float* __restrict__ w1, const float* __restrict__ b1,
    ushort* __restrict__ x1p)
{
    int wid = (blockIdx.x * 256 + threadIdx.x) >> 6;
    int lane = threadIdx.x & 63;
    int b = wid / 41, y = wid % 41;
    float acc[34];
    float bias = b1[lane];
    #pragma unroll
    for (int x = 0; x < 34; ++x) acc[x] = bias;
    #pragma unroll 1
    for (int ky = 0; ky < 5; ++ky) {
        int iy = 2 * y + ky - 1;
        if (iy < 0 || iy >= HH) continue;
        const float* hrow = hin + (size_t)b * PIX + iy * WW;
        const float* trow = tar + ((size_t)b * PIX + iy * WW) * 5;
        #pragma unroll 1
        for (int kx = 0; kx < 5; ++kx) {
            float w[6];
            #pragma unroll
            for (int ci = 0; ci < 6; ++ci)
                w[ci] = w1[((ky * 5 + kx) * 6 + ci) * 64 + lane];
            #pragma unroll
            for (int x = 0; x < 34; ++x) {
                int ix = 2 * x + kx - 2;
                if (ix < 0 || ix >= WW) continue;
                float v0 = hrow[ix];
                acc[x] += v0 * w[0];
                #pragma unroll
                for (int c = 0; c < 5; ++c)
                    acc[x] += trow[ix * 5 + c] * w[c + 1];
            }
        }
    }
    ushort* obase = x1p + ((size_t)(b * 45 + y + 2) * 37) * 64;
    #pragma unroll
    for (int x = 0; x < 34; ++x)
        obase[(x + 1) * 64 + lane] = (ushort)bf16rne(lrelu(acc[x]));
}

// ---------------- Weight transpose+cvt: wt[n][k] = bf16(w[k][n]) ----------------
__global__ __launch_bounds__(256) void k_wt(
    const float* __restrict__ w, ushort* __restrict__ wt, int K, int N)
{
    int idx = blockIdx.x * 256 + threadIdx.x;
    if (idx >= K * N) return;
    int n = idx / K, k = idx % K;
    wt[idx] = (ushort)bf16rne(w[(size_t)k * N + n]);
}

// ---------------- MFMA implicit-GEMM conv (conv2 / conv3) ----------------
template<bool IS3>
__global__ __launch_bounds__(256) void k_convm(
    const ushort* __restrict__ Ain, const ushort* __restrict__ Bt,
    const float* __restrict__ p0, const float* __restrict__ p1,
    const float* __restrict__ p2, const float* __restrict__ p3,
    ushort* __restrict__ outp)
{
    constexpr int OH = IS3 ? 20 : 21, OW = IS3 ? 16 : 17;
    constexpr int PH = IS3 ? 23 : 45, PW = IS3 ? 19 : 37;
    constexpr int CIN = IS3 ? 128 : 64;
    constexpr int KW_ = IS3 ? 4 : 5;
    constexpr int KK  = IS3 ? 16 : 25;
    constexpr int STR = IS3 ? 1 : 2;
    constexpr int HALVES = CIN / 64;
    constexpr int MPB = OH * OW;
    constexpr int M = 64 * MPB;
    constexpr int KTOT = KK * CIN;

    __shared__ ushort At[128 * 64];
    __shared__ ushort Bl[128 * 64];

    const int tid = threadIdx.x;
    const int wid = tid >> 6, lane = tid & 63;
    const int m0 = blockIdx.x * 128;
    const int n0 = blockIdx.y * 128;
    const int wr = wid >> 1, wc = wid & 1;

    const int swz = (((lane & 7) ^ ((lane >> 3) & 7)) << 3);

    int arow_base[4], brow_base[4];
    #pragma unroll
    for (int i = 0; i < 4; ++i) {
        int row = wid * 32 + i * 8 + (lane >> 3);
        int m = m0 + row; if (m > M - 1) m = M - 1;
        int b = m / MPB, r = m % MPB;
        int y = r / OW, x = r % OW;
        arow_base[i] = ((b * PH + y * STR) * PW + x * STR) * CIN;
        brow_base[i] = (n0 + row) * KTOT;
    }

    f32x4 acc[4][4];
    #pragma unroll
    for (int i = 0; i < 4; ++i)
        #pragma unroll
        for (int j = 0; j < 4; ++j) acc[i][j] = (f32x4){0.f, 0.f, 0.f, 0.f};

    #pragma unroll 1
    for (int kp = 0; kp < KK; ++kp) {
        const int ky = kp / KW_, kx = kp % KW_;
        const int aoff = (ky * PW + kx) * CIN;
        #pragma unroll
        for (int h = 0; h < HALVES; ++h) {
            const int koff = h * 64;
            #pragma unroll
            for (int i = 0; i < 4; ++i) {
                gload16(Ain + arow_base[i] + aoff + koff + swz,
                        (void*)(At + (wid * 32 + i * 8) * 64));
                gload16(Bt + brow_base[i] + kp * CIN + koff + swz,
                        (void*)(Bl + (wid * 32 + i * 8) * 64));
            }
            __syncthreads();
            #pragma unroll
            for (int ks = 0; ks < 2; ++ks) {
                short8 af[4], bf[4];
                const int lc = ks * 64 + ((lane >> 4) << 4);
                #pragma unroll
                for (int mf = 0; mf < 4; ++mf) {
                    int row = wr * 64 + mf * 16 + (lane & 15);
                    af[mf] = *(const short8*)((const char*)At + row * 128 + (lc ^ ((row & 7) << 4)));
                }
                #pragma unroll
                for (int nf = 0; nf < 4; ++nf) {
                    int row = wc * 64 + nf * 16 + (lane & 15);
                    bf[nf] = *(const short8*)((const char*)Bl + row * 128 + (lc ^ ((row & 7) << 4)));
                }
                #pragma unroll
                for (int mf = 0; mf < 4; ++mf)
                    #pragma unroll
                    for (int nf = 0; nf < 4; ++nf)
                        acc[mf][nf] = __builtin_amdgcn_mfma_f32_16x16x32_bf16(
                            af[mf], bf[nf], acc[mf][nf], 0, 0, 0);
            }
            __syncthreads();
        }
    }

    if (IS3) {
        #pragma unroll
        for (int nf = 0; nf < 4; ++nf) {
            int n = n0 + wc * 64 + nf * 16 + (lane & 15);
            float sc = p0[n] * rsqrtf(p3[n] + 1e-3f);
            float sh = p1[n] - p2[n] * sc;
            #pragma unroll
            for (int mf = 0; mf < 4; ++mf) {
                int mbase = m0 + wr * 64 + mf * 16 + ((lane >> 4) << 2);
                #pragma unroll
                for (int r = 0; r < 4; ++r) {
                    float v = lrelu(acc[mf][nf][r] * sc + sh);
                    outp[(size_t)(mbase + r) * 512 + n] = (ushort)bf16rne(v);
                }
            }
        }
    } else {
        #pragma unroll
        for (int nf = 0; nf < 4; ++nf) {
            int n = wc * 64 + nf * 16 + (lane & 15);
            float bias = p0[n];
            #pragma unroll
            for (int mf = 0; mf < 4; ++mf) {
                int mbase = m0 + wr * 64 + mf * 16 + ((lane >> 4) << 2);
                #pragma unroll
                for (int r = 0; r < 4; ++r) {
                    int m = mbase + r;
                    if (m < M) {
                        int b = m / MPB, rr = m % MPB;
                        int y = rr / OW, x = rr % OW;
                        float v = lrelu(acc[mf][nf][r] + bias);
                        outp[((size_t)((b * 23) + (y + 1)) * 19 + (x + 1)) * 128 + n] =
                            (ushort)bf16rne(v);
                    }
                }
            }
        }
    }
}

// ---------------- Kernel 6: pad1 + conv4 4x4 VALID, 512->1, +bias (bf16 in) ----------------
__global__ __launch_bounds__(64) void k_conv4(
    const ushort* __restrict__ x3, const float* __restrict__ w4,
    const float* __restrict__ b4, float* __restrict__ out)
{
    int b = blockIdx.x / 19, y = blockIdx.x % 19;
    int lane = threadIdx.x;
    int c0 = lane * 8;
    float acc[15];
    #pragma unroll
    for (int x = 0; x < 15; ++x) acc[x] = 0.f;
    #pragma unroll 1
    for (int ky = 0; ky < 4; ++ky) {
        int iy = y + ky - 1;
        if (iy < 0 || iy >= 20) continue;
        float w[4][8];
        #pragma unroll
        for (int kx = 0; kx < 4; ++kx) {
            const float4 wa = *(const float4*)(w4 + (ky * 4 + kx) * 512 + c0);
            const float4 wb = *(const float4*)(w4 + (ky * 4 + kx) * 512 + c0 + 4);
            w[kx][0] = wa.x; w[kx][1] = wa.y; w[kx][2] = wa.z; w[kx][3] = wa.w;
            w[kx][4] = wb.x; w[kx][5] = wb.y; w[kx][6] = wb.z; w[kx][7] = wb.w;
        }
        #pragma unroll 1
        for (int ix = 0; ix < 16; ++ix) {
            uint4 u = *(const uint4*)(x3 + ((size_t)(b * 20 + iy) * 16 + ix) * 512 + c0);
            float v[8];
            v[0] = bf16tof(u.x); v[1] = bf16tof(u.x >> 16);
            v[2] = bf16tof(u.y); v[3] = bf16tof(u.y >> 16);
            v[4] = bf16tof(u.z); v[5] = bf16tof(u.z >> 16);
            v[6] = bf16tof(u.w); v[7] = bf16tof(u.w >> 16);
            #pragma unroll
            for (int kx = 0; kx < 4; ++kx) {
                int x = ix - kx + 1;
                if (x < 0 || x > 14) continue;
                float s = 0.f;
                #pragma unroll
                for (int c = 0; c < 8; ++c) s = fmaf(v[c], w[kx][c], s);
                acc[x] += s;
            }
        }
    }
    float bias = b4[0];
    #pragma unroll
    for (int x = 0; x < 15; ++x) {
        float s = acc[x];
        #pragma unroll
        for (int off = 32; off > 0; off >>= 1)
            s += __shfl_down(s, off);
        if (lane == 0) out[(size_t)blockIdx.x * 15 + x] = s + bias;
    }
}

extern "C" void kernel_launch(void* const* d_in, const int* in_sizes, int n_in,
                              void* d_out, int out_size, void* d_ws, size_t ws_size,
                              hipStream_t stream)
{
    const float* inp  = (const float*)d_in[0];
    const float* tar  = (const float*)d_in[1];
    const float* wx   = (const float*)d_in[2];
    const float* wh   = (const float*)d_in[3];
    const float* bl   = (const float*)d_in[4];
    const float* w1   = (const float*)d_in[5];
    const float* b1   = (const float*)d_in[6];
    const float* w2   = (const float*)d_in[7];
    const float* b2   = (const float*)d_in[8];
    const float* w3   = (const float*)d_in[9];
    const float* gam  = (const float*)d_in[10];
    const float* bet  = (const float*)d_in[11];
    const float* mean = (const float*)d_in[12];
    const float* var  = (const float*)d_in[13];
    const float* w4   = (const float*)d_in[14];
    const float* b4   = (const float*)d_in[15];
    float* out = (float*)d_out;

    char* ws = (char*)d_ws;
    uint2*  xz   = (uint2*)(ws);
    ushort* x3b  = (ushort*)(ws);
    float*  hfin = (float*)(ws + 67510272);
    ushort* x1p  = (ushort*)(ws + 68916736);
    ushort* x2p  = (ushort*)(ws + 82556416);
    ushort* w2t  = (ushort*)(ws + 89716224);
    ushort* w3t  = (ushort*)(ws + 90125824);

    hipMemsetAsync(x1p, 0, 13639680, stream);
    hipMemsetAsync(x2p, 0, 7159808, stream);

    k_wt<<<(128 * 1600 + 255) / 256, 256, 0, stream>>>(w2, w2t, 1600, 128);
    k_wt<<<(512 * 2048 + 255) / 256, 256, 0, stream>>>(w3, w3t, 2048, 512);

    k_xz<<<1536 * 6, 256, 0, stream>>>(inp, wx, bl, xz);
    k_lstm<<<BB, 1024, 0, stream>>>(xz, wh, hfin);
    k_conv1<<<656, 256, 0, stream>>>(hfin, tar, w1, b1, x1p);

    dim3 g2(179, 1);
    k_convm<false><<<g2, 256, 0, stream>>>(x1p, w2t, b2, nullptr, nullptr, nullptr, x2p);
    dim3 g3(160, 4);
    k_convm<true><<<g3, 256, 0, stream>>>(x2p, w3t, gam, bet, mean, var, x3b);

    k_conv4<<<BB * 19, 64, 0, stream>>>(x3b, w4, b4, out);
}